// Round 4
// baseline (8193.555 us; speedup 1.0000x reference)
//
#include <hip/hip_runtime.h>

// LSTMTagger: B=32 T=512 V=32000 E=512 H=1024 (4H=4096) O=128
// Inputs: float tensors fp32, ints int32. Output: fp32 (d_out is float*).
// Compute: bf16 MFMA (fp32 accumulate) for gates; fp32 VALU for output logits.
//
// ws layout (bytes) -- total 221184 (216 KB):
//   [0, 131072)        hbuf:  ushort[4 groups][2 bufs][8192]  (h in A-staging order)
//   [131072, 139264)   cnt:   uint[4 groups][512]             (per-step arrival counters)
//   [139264, 204800)   vrows: ushort[32][1024]                (h at verb index per batch)
//   [204800, 221184)   vlog:  float[32][128]                  (verb logits + b_lin)

typedef short s8v __attribute__((ext_vector_type(8)));
typedef float f4v __attribute__((ext_vector_type(4)));

#define WS_CNT_OFF   131072
#define WS_VROWS_OFF 139264
#define WS_VLOG_OFF  204800

__device__ __forceinline__ float b2f(unsigned short u) {
    union { unsigned int i; float f; } x; x.i = ((unsigned int)u) << 16; return x.f;
}
__device__ __forceinline__ unsigned short f2b(float f) {
    union { float f; unsigned int i; } x; x.f = f;
    unsigned int r = (x.i + 0x7fffu + ((x.i >> 16) & 1u)) >> 16;
    return (unsigned short)r;
}

__global__ void init_kernel(unsigned int* ws) {
    int i = blockIdx.x * 256 + threadIdx.x;
    if (i < 34816) ws[i] = 0u;   // zero hbuf (131072B) + cnt (8192B)
}

// Distributed output projection: this WG computes output cols {2w, 2w+1} of
// logits[b0..b0+7, tproj, :] = h(tproj) . Wo^T from hA (fp32 accumulate,
// fp32 store directly to dout). 256 threads = 16 (b,oc) pairs x 16 k-parts.
__device__ __forceinline__ void project_cols(
    const short* hA, const float* __restrict__ Wr0, const float* __restrict__ Wr1,
    float* __restrict__ dout, int b0, int tproj, int w, int tid)
{
    const int pair = tid >> 4;          // 0..15
    const int part = tid & 15;          // k = j*16 + part
    const int b = pair >> 1, oc = pair & 1;
    const float* wr = oc ? Wr1 : Wr0;
    float acc = 0.f;
#pragma unroll 16
    for (int j = 0; j < 64; ++j) {
        int k = j * 16 + part;
        float hv = b2f((unsigned short)hA[((k >> 3) * 16 + b) * 8 + (k & 7)]);
        acc += hv * wr[k];
    }
    for (int off = 1; off < 16; off <<= 1) acc += __shfl_xor(acc, off);
    if (part == 0)
        dout[((size_t)(b0 + b) * 512 + tproj) * 128 + 2 * w + oc] = acc;
}

// ---------------------------------------------------------------------------
// Persistent LSTM scan. 256 WGs = 4 groups x 64 WGs. Group g: batches [8g,8g+8).
// WG w: hidden units [16w,16w+16) -> 64 gate columns. Wave v of 4: 16 cols
// n = gate*1024 + 16w + 4v + (c&3), gate = c>>2, c = lane&15.
// W_hh/W_ih slices converted fp32->bf16 once into VGPRs for all 512 steps.
// Output projection of h(t-2) runs in the barrier-wait shadow each step.
// ---------------------------------------------------------------------------
__global__ __launch_bounds__(256, 1) void scan_kernel(
    const int* __restrict__ tokens,
    const int* __restrict__ vidx,
    const float* __restrict__ emb,
    const float* __restrict__ W_ih,
    const float* __restrict__ W_hh,
    const float* __restrict__ b_ih,
    const float* __restrict__ b_hh,
    const float* __restrict__ W_lin,
    unsigned short* __restrict__ hbuf,     // ws
    unsigned int* __restrict__ cnt,        // ws
    unsigned short* __restrict__ vrows,    // ws
    float* __restrict__ dout)              // d_out (raw logits, fp32)
{
    __shared__ short hA[128 * 16 * 8];   // 32 KB  (K=1024 recurrent A-tiles)
    __shared__ short eA[64 * 16 * 8];    // 16 KB  (K=512 embedding A-tiles)
    __shared__ float gbuf[16 * 64];      //  4 KB  gates f32

    const int tid  = threadIdx.x;
    const int g    = blockIdx.x >> 6;
    const int w    = blockIdx.x & 63;
    const int b0   = g * 8;
    const int lane = tid & 63;
    const int v    = tid >> 6;
    const int q    = lane >> 4;
    const int c    = lane & 15;

    const float* Wr0 = W_lin + (size_t)(2 * w) * 2048 + 1024;       // Wo rows
    const float* Wr1 = W_lin + (size_t)(2 * w + 1) * 2048 + 1024;

    // --- preload B fragments, fp32 -> bf16 (kept in VGPRs for all 512 steps) ---
    const int n = ((c >> 2) * 1024) + 16 * w + 4 * v + (c & 3);
    s8v Bh[32], Be[16];
    {
        const float* rh = W_hh + (size_t)n * 1024;
#pragma unroll
        for (int ks = 0; ks < 32; ++ks) {
            const float* s = rh + ks * 32 + q * 8;
            f4v lo = *(const f4v*)s, hi = *(const f4v*)(s + 4);
            s8v f;
#pragma unroll
            for (int j = 0; j < 4; ++j) { f[j] = (short)f2b(lo[j]); f[j + 4] = (short)f2b(hi[j]); }
            Bh[ks] = f;
        }
        const float* re = W_ih + (size_t)n * 512;
#pragma unroll
        for (int ks = 0; ks < 16; ++ks) {
            const float* s = re + ks * 32 + q * 8;
            f4v lo = *(const f4v*)s, hi = *(const f4v*)(s + 4);
            s8v f;
#pragma unroll
            for (int j = 0; j < 4; ++j) { f[j] = (short)f2b(lo[j]); f[j + 4] = (short)f2b(hi[j]); }
            Be[ks] = f;
        }
    }

    // zero MFMA pad rows 8..15 (written once, never touched again)
    const s8v zv = {0,0,0,0,0,0,0,0};
    for (int i = tid; i < 1024; i += 256) { int ko = i >> 3, r = 8 + (i & 7);
        *(s8v*)&hA[(ko * 16 + r) * 8] = zv; }
    for (int i = tid; i < 512; i += 256) { int ko = i >> 3, r = 8 + (i & 7);
        *(s8v*)&eA[(ko * 16 + r) * 8] = zv; }

    // pointwise threads (tid<128): (batch pb, hidden pj); c-state in register
    float cst = 0.f, bi = 0.f, bff = 0.f, bg = 0.f, bo = 0.f;
    int tvb = -1;
    const int pb = tid >> 4, pj = tid & 15;
    if (tid < 128) {
        int nn = 16 * w + pj;
        bi  = b_ih[nn]        + b_hh[nn];
        bff = b_ih[1024 + nn] + b_hh[1024 + nn];
        bg  = b_ih[2048 + nn] + b_hh[2048 + nn];
        bo  = b_ih[3072 + nn] + b_hh[3072 + nn];
        tvb = vidx[b0 + pb];
    }

    unsigned short* hb = hbuf + g * 2 * 8192;
    unsigned int*   mycnt = cnt + g * 512;
    int p = 0;
    __syncthreads();

    for (int t = 0; t < 512; ++t) {
        // ---- stage e_t (gathered embedding rows, fp32->bf16) ----
        for (int i = tid; i < 512; i += 256) {
            int ko = i >> 3, b = i & 7;
            int tok = tokens[(b0 + b) * 512 + t];
            const float* s = emb + (size_t)tok * 512 + ko * 8;
            f4v lo = *(const f4v*)s, hi = *(const f4v*)(s + 4);
            s8v f;
#pragma unroll
            for (int j = 0; j < 4; ++j) { f[j] = (short)f2b(lo[j]); f[j + 4] = (short)f2b(hi[j]); }
            *(s8v*)&eA[(ko * 16 + b) * 8] = f;
        }
        __syncthreads();

        f4v acc = {0.f, 0.f, 0.f, 0.f};
        // ---- e-part MFMA (K=512): independent of h(t-1) ----
#pragma unroll
        for (int ks = 0; ks < 16; ++ks) {
            s8v a = *(const s8v*)&eA[((ks * 4 + q) * 16 + c) * 8];
            acc = __builtin_amdgcn_mfma_f32_16x16x32_bf16(a, Be[ks], acc, 0, 0, 0);
        }

        // ---- output projection of h(t-2) (hA content) in the wait shadow ----
        if (t >= 2)
            project_cols(hA, Wr0, Wr1, dout, b0, t - 2, w, tid);

        // ---- wait for h(t-1) from all 64 WGs of this group ----
        if (t > 0) {
            if (tid == 0) {
                while (__hip_atomic_load(&mycnt[t - 1], __ATOMIC_RELAXED,
                                         __HIP_MEMORY_SCOPE_AGENT) < 64u)
                    __builtin_amdgcn_s_sleep(1);
            }
            __syncthreads();   // also orders project_cols reads before hA overwrite
            __builtin_amdgcn_fence(__ATOMIC_ACQUIRE, "agent");
        }

        // ---- stage h(t-1) (already in A-fragment order, bf16) ----
        {
            const unsigned short* src = hb + p * 8192;
            for (int i = tid; i < 1024; i += 256) {
                int ko = i >> 3, b = i & 7;
                *(s8v*)&hA[(ko * 16 + b) * 8] = *(const s8v*)(src + i * 8);
            }
        }
        __syncthreads();

        // ---- h-part MFMA (K=1024) ----
#pragma unroll
        for (int ks = 0; ks < 32; ++ks) {
            s8v a = *(const s8v*)&hA[((ks * 4 + q) * 16 + c) * 8];
            acc = __builtin_amdgcn_mfma_f32_16x16x32_bf16(a, Bh[ks], acc, 0, 0, 0);
        }

        // ---- dump gates ----
#pragma unroll
        for (int r = 0; r < 4; ++r)
            gbuf[(q * 4 + r) * 64 + v * 16 + c] = acc[r];
        __syncthreads();

        // ---- pointwise LSTM cell (128 threads: 8 batches x 16 hidden) ----
        if (tid < 128) {
            int base = (pj >> 2) * 16, cb = pj & 3;
            float xi = gbuf[pb * 64 + base + cb]       + bi;
            float xf = gbuf[pb * 64 + base + 4 + cb]   + bff;
            float xg = gbuf[pb * 64 + base + 8 + cb]   + bg;
            float xo = gbuf[pb * 64 + base + 12 + cb]  + bo;
            float ig = 1.f / (1.f + expf(-xi));
            float fg = 1.f / (1.f + expf(-xf));
            float gg = tanhf(xg);
            float og = 1.f / (1.f + expf(-xo));
            cst = fg * cst + ig * gg;
            float h = og * tanhf(cst);
            unsigned short hbits = f2b(h);
            int jg = 16 * w + pj;
            hb[(p ^ 1) * 8192 + ((jg >> 3) * 8 + pb) * 8 + (jg & 7)] = hbits;
            if (t == tvb) vrows[(b0 + pb) * 1024 + jg] = hbits;
        }
        __syncthreads();   // drain writes (vmcnt(0) before s_barrier)

        if (tid == 0)
            __hip_atomic_fetch_add(&mycnt[t], 1u, __ATOMIC_RELEASE,
                                   __HIP_MEMORY_SCOPE_AGENT);
        p ^= 1;
    }

    // ---- tail: project h(510) (still in hA), then fetch & project h(511) ----
    project_cols(hA, Wr0, Wr1, dout, b0, 510, w, tid);
    if (tid == 0) {
        while (__hip_atomic_load(&mycnt[511], __ATOMIC_RELAXED,
                                 __HIP_MEMORY_SCOPE_AGENT) < 64u)
            __builtin_amdgcn_s_sleep(1);
    }
    __syncthreads();
    __builtin_amdgcn_fence(__ATOMIC_ACQUIRE, "agent");
    {
        const unsigned short* src = hb + p * 8192;   // p == 0: h(511)
        for (int i = tid; i < 1024; i += 256) {
            int ko = i >> 3, b = i & 7;
            *(s8v*)&hA[(ko * 16 + b) * 8] = *(const s8v*)(src + i * 8);
        }
    }
    __syncthreads();
    project_cols(hA, Wr0, Wr1, dout, b0, 511, w, tid);
}

// ---------------------------------------------------------------------------
// vlog[b][o] = vrows[b,:] . Wv[o,:] + b_lin[o]   (Wv = first half of W_lin)
// ---------------------------------------------------------------------------
__global__ void verb_kernel(const unsigned short* __restrict__ vrows,
                            const float* __restrict__ W_lin,
                            const float* __restrict__ b_lin,
                            float* __restrict__ vlog)
{
    __shared__ float vrow[1024];
    int b = blockIdx.x, tid = threadIdx.x;
    for (int i = tid; i < 1024; i += 256) vrow[i] = b2f(vrows[b * 1024 + i]);
    __syncthreads();
    if (tid < 128) {
        float acc = 0.f;
        const float* wr = W_lin + (size_t)tid * 2048;
        for (int h = 0; h < 1024; ++h) acc += vrow[h] * wr[h];
        vlog[b * 128 + tid] = acc + b_lin[tid];
    }
}

// ---------------------------------------------------------------------------
// In-place finalize: dout[b,t,:] = log_softmax(dout[b,t,:] + vlog[b,:]).
// 8 threads per row, 16 cols each; 32 rows per WG. All fp32.
// ---------------------------------------------------------------------------
__global__ void softmax_kernel(float* __restrict__ dout,
                               const float* __restrict__ vlog)
{
    int tid = threadIdx.x;
    int grow = blockIdx.x * 32 + (tid >> 3);   // global (b*512+t) row
    int part = tid & 7;
    int b = grow >> 9;
    float* pp = dout + (size_t)grow * 128 + part * 16;
    const float* vb = vlog + b * 128 + part * 16;
    float L[16];
#pragma unroll
    for (int i = 0; i < 16; ++i) L[i] = pp[i] + vb[i];
    float m = L[0];
#pragma unroll
    for (int i = 1; i < 16; ++i) m = fmaxf(m, L[i]);
    for (int off = 1; off < 8; off <<= 1) m = fmaxf(m, __shfl_xor(m, off));
    float s = 0.f;
#pragma unroll
    for (int i = 0; i < 16; ++i) s += expf(L[i] - m);
    for (int off = 1; off < 8; off <<= 1) s += __shfl_xor(s, off);
    float lz = m + logf(s);
#pragma unroll
    for (int i = 0; i < 16; ++i) pp[i] = L[i] - lz;
}

extern "C" void kernel_launch(void* const* d_in, const int* in_sizes, int n_in,
                              void* d_out, int out_size, void* d_ws, size_t ws_size,
                              hipStream_t stream) {
    const int*   tokens = (const int*)d_in[0];
    const int*   vidx   = (const int*)d_in[1];
    const float* emb    = (const float*)d_in[2];
    const float* W_ih   = (const float*)d_in[3];
    const float* W_hh   = (const float*)d_in[4];
    const float* b_ih   = (const float*)d_in[5];
    const float* b_hh   = (const float*)d_in[6];
    const float* W_lin  = (const float*)d_in[7];
    const float* b_lin  = (const float*)d_in[8];
    float* dout = (float*)d_out;

    char* ws = (char*)d_ws;
    unsigned short* hbuf  = (unsigned short*)ws;
    unsigned int*   cnt   = (unsigned int*)(ws + WS_CNT_OFF);
    unsigned short* vrows = (unsigned short*)(ws + WS_VROWS_OFF);
    float*          vlog  = (float*)(ws + WS_VLOG_OFF);

    init_kernel<<<136, 256, 0, stream>>>((unsigned int*)ws);
    scan_kernel<<<256, 256, 0, stream>>>(tokens, vidx, emb, W_ih, W_hh, b_ih, b_hh,
                                         W_lin, hbuf, cnt, vrows, dout);
    verb_kernel<<<32, 256, 0, stream>>>(vrows, W_lin, b_lin, vlog);
    softmax_kernel<<<512, 256, 0, stream>>>(dout, vlog);
}

// Round 5
// 3453.340 us; speedup vs baseline: 2.3726x; 2.3726x over previous
//
#include <hip/hip_runtime.h>

// LSTMTagger: B=32 T=512 V=32000 E=512 H=1024 (4H=4096) O=128
// Inputs fp32/int32; output fp32. bf16 MFMA w/ fp32 accumulate for gates.
//
// Cross-WG protocol (per timestep, per group of 64 WGs): NO fences (agent
// fences invalidate/writeback whole per-XCD L2 on gfx950 -> 16us/step in R4).
// Instead all communicated data (hbuf, cnt) uses relaxed agent-scope atomics
// (lowered to sc0/sc1 loads/stores, coherent at LLC). Producer stores drain at
// the compiler-emitted s_waitcnt vmcnt(0) before s_barrier; then one relaxed
// fetch_add publishes; consumers spin on the counter, then atomic-load h.
//
// ws layout (bytes) -- total 221184:
//   [0, 131072)        hbuf:  ushort[4 groups][2 bufs][8192]
//   [131072, 139264)   cnt:   uint[4 groups][512]
//   [139264, 204800)   vrows: ushort[32][1024]
//   [204800, 221184)   vlog:  float[32][128]

typedef short s8v __attribute__((ext_vector_type(8)));
typedef float f4v __attribute__((ext_vector_type(4)));

#define WS_CNT_OFF   131072
#define WS_VROWS_OFF 139264
#define WS_VLOG_OFF  204800

__device__ __forceinline__ float b2f(unsigned short u) {
    union { unsigned int i; float f; } x; x.i = ((unsigned int)u) << 16; return x.f;
}
__device__ __forceinline__ unsigned short f2b(float f) {
    union { float f; unsigned int i; } x; x.f = f;
    unsigned int r = (x.i + 0x7fffu + ((x.i >> 16) & 1u)) >> 16;
    return (unsigned short)r;
}
__device__ __forceinline__ float blo(unsigned int u) {
    union { unsigned int i; float f; } x; x.i = u << 16; return x.f;
}
__device__ __forceinline__ float bhi(unsigned int u) {
    union { unsigned int i; float f; } x; x.i = u & 0xffff0000u; return x.f;
}

__global__ void init_kernel(unsigned int* ws) {
    int i = blockIdx.x * 256 + threadIdx.x;
    if (i < 34816) ws[i] = 0u;   // zero hbuf (131072B) + cnt (8192B)
}

// Distributed output projection: WG computes cols {2w,2w+1} of
// logits[b0..b0+7, tproj, :] from hA (LDS, ko-stride 17 units).
// 256 threads = 16 (b,oc) pairs x 16 k-parts; ds_read_b128 + fp32 FMA.
__device__ __forceinline__ void project_cols(
    const short* hA, const float* __restrict__ Wr0, const float* __restrict__ Wr1,
    float* __restrict__ dout, int b0, int tproj, int w, int tid)
{
    const int pair = tid >> 4, p = tid & 15;
    const int b = pair >> 1, oc = pair & 1;
    const float* wr = oc ? Wr1 : Wr0;
    float acc = 0.f;
#pragma unroll
    for (int j = 0; j < 8; ++j) {
        int ko = j * 16 + p;
        const unsigned int* d = (const unsigned int*)&hA[(ko * 17 + b) * 8];
        const float* wk = wr + ko * 8;
        f4v w0 = *(const f4v*)wk, w1 = *(const f4v*)(wk + 4);
        unsigned int d0 = d[0], d1 = d[1], d2 = d[2], d3 = d[3];
        acc += blo(d0) * w0[0] + bhi(d0) * w0[1] + blo(d1) * w0[2] + bhi(d1) * w0[3]
             + blo(d2) * w1[0] + bhi(d2) * w1[1] + blo(d3) * w1[2] + bhi(d3) * w1[3];
    }
#pragma unroll
    for (int off = 1; off < 16; off <<= 1) acc += __shfl_xor(acc, off);
    if (p == 0)
        dout[((size_t)(b0 + b) * 512 + tproj) * 128 + 2 * w + oc] = acc;
}

// ---------------------------------------------------------------------------
// Persistent LSTM scan. 256 WGs = 4 groups x 64 WGs. Group g: batches [8g,8g+8).
// WG w: hidden [16w,16w+16) -> 64 gate cols; wave v: cols n = gate*1024+16w+4v+(c&3).
// W_hh/W_ih slices fp32->bf16 once into VGPRs (192 VGPRs) for all 512 steps.
// ---------------------------------------------------------------------------
__global__ __launch_bounds__(256, 1) void scan_kernel(
    const int* __restrict__ tokens,
    const int* __restrict__ vidx,
    const float* __restrict__ emb,
    const float* __restrict__ W_ih,
    const float* __restrict__ W_hh,
    const float* __restrict__ b_ih,
    const float* __restrict__ b_hh,
    const float* __restrict__ W_lin,
    unsigned short* __restrict__ hbuf,
    unsigned int* __restrict__ cnt,
    unsigned short* __restrict__ vrows,
    float* __restrict__ dout)
{
    __shared__ short hA[128 * 17 * 8];   // 34816 B (K=1024, ko-stride 17 units)
    __shared__ short eA[64 * 17 * 8];    // 17408 B (K=512)
    __shared__ float gbuf[16 * 65];      //  4160 B gates f32 (stride 65)

    const int tid  = threadIdx.x;
    const int g    = blockIdx.x >> 6;
    const int w    = blockIdx.x & 63;
    const int b0   = g * 8;
    const int lane = tid & 63;
    const int v    = tid >> 6;
    const int q    = lane >> 4;
    const int c    = lane & 15;

    const float* Wr0 = W_lin + (size_t)(2 * w) * 2048 + 1024;   // Wo rows
    const float* Wr1 = W_lin + (size_t)(2 * w + 1) * 2048 + 1024;

    // --- preload B fragments, fp32 -> bf16 (VGPR-resident all 512 steps) ---
    const int n = ((c >> 2) * 1024) + 16 * w + 4 * v + (c & 3);
    s8v Bh[32], Be[16];
    {
        const float* rh = W_hh + (size_t)n * 1024;
#pragma unroll
        for (int ks = 0; ks < 32; ++ks) {
            const float* s = rh + ks * 32 + q * 8;
            f4v lo = *(const f4v*)s, hi = *(const f4v*)(s + 4);
            s8v f;
#pragma unroll
            for (int j = 0; j < 4; ++j) { f[j] = (short)f2b(lo[j]); f[j + 4] = (short)f2b(hi[j]); }
            Bh[ks] = f;
        }
        const float* re = W_ih + (size_t)n * 512;
#pragma unroll
        for (int ks = 0; ks < 16; ++ks) {
            const float* s = re + ks * 32 + q * 8;
            f4v lo = *(const f4v*)s, hi = *(const f4v*)(s + 4);
            s8v f;
#pragma unroll
            for (int j = 0; j < 4; ++j) { f[j] = (short)f2b(lo[j]); f[j + 4] = (short)f2b(hi[j]); }
            Be[ks] = f;
        }
    }

    // zero MFMA pad rows 8..15 (written once)
    const s8v zv = {0,0,0,0,0,0,0,0};
    for (int i = tid; i < 1024; i += 256) { int ko = i >> 3, r = 8 + (i & 7);
        *(s8v*)&hA[(ko * 17 + r) * 8] = zv; }
    for (int i = tid; i < 512; i += 256) { int ko = i >> 3, r = 8 + (i & 7);
        *(s8v*)&eA[(ko * 17 + r) * 8] = zv; }

    // pointwise threads (tid<64): batch pb = tid>>3, hidden pair pj2 = tid&7
    float cst0 = 0.f, cst1 = 0.f;
    float bi0 = 0, bf0 = 0, bg0 = 0, bo0 = 0, bi1 = 0, bf1 = 0, bg1 = 0, bo1 = 0;
    int tvb = -1;
    const int pb = tid >> 3, pj2 = tid & 7;
    if (tid < 64) {
        int n0 = 16 * w + 2 * pj2, n1 = n0 + 1;
        bi0 = b_ih[n0]        + b_hh[n0];        bi1 = b_ih[n1]        + b_hh[n1];
        bf0 = b_ih[1024 + n0] + b_hh[1024 + n0]; bf1 = b_ih[1024 + n1] + b_hh[1024 + n1];
        bg0 = b_ih[2048 + n0] + b_hh[2048 + n0]; bg1 = b_ih[2048 + n1] + b_hh[2048 + n1];
        bo0 = b_ih[3072 + n0] + b_hh[3072 + n0]; bo1 = b_ih[3072 + n1] + b_hh[3072 + n1];
        tvb = vidx[b0 + pb];
    }

    unsigned short* hb   = hbuf + g * 2 * 8192;
    unsigned int*   hb32 = (unsigned int*)hb;
    unsigned int*   mycnt = cnt + g * 512;
    const int dwidx = ((2 * w + (pj2 >> 2)) * 8 + pb) * 4 + (pj2 & 3);
    int rp = 0;
    __syncthreads();

    for (int t = 0; t < 512; ++t) {
        // ---- stage e_t (gathered embedding rows, fp32->bf16, L2-cached) ----
        for (int i = tid; i < 512; i += 256) {
            int ko = i >> 3, b = i & 7;
            int tok = tokens[(b0 + b) * 512 + t];
            const float* s = emb + (size_t)tok * 512 + ko * 8;
            f4v lo = *(const f4v*)s, hi = *(const f4v*)(s + 4);
            s8v f;
#pragma unroll
            for (int j = 0; j < 4; ++j) { f[j] = (short)f2b(lo[j]); f[j + 4] = (short)f2b(hi[j]); }
            *(s8v*)&eA[(ko * 17 + b) * 8] = f;
        }

        // ---- output projection of h(t-2) (current hA) -- shadow work ----
        if (t >= 2)
            project_cols(hA, Wr0, Wr1, dout, b0, t - 2, w, tid);

        __syncthreads();   // eA staged AND hA reads done (before overwrite)

        // ---- e-part MFMA (K=512) ----
        f4v ae = {0.f, 0.f, 0.f, 0.f};
#pragma unroll
        for (int ks = 0; ks < 16; ++ks) {
            s8v a = *(const s8v*)&eA[((ks * 4 + q) * 17 + c) * 8];
            ae = __builtin_amdgcn_mfma_f32_16x16x32_bf16(a, Be[ks], ae, 0, 0, 0);
        }

        // ---- wait for h(t-1): all threads spin on LLC counter (no fence) ----
        if (t > 0) {
            while (__hip_atomic_load(&mycnt[t - 1], __ATOMIC_RELAXED,
                                     __HIP_MEMORY_SCOPE_AGENT) < 64u) {}
        }

        // ---- stage h(t-1): qword LLC-coherent loads -> LDS ----
        {
            const unsigned long long* src =
                (const unsigned long long*)(hb + rp * 8192);
#pragma unroll
            for (int it = 0; it < 8; ++it) {
                int j = it * 256 + tid;
                unsigned long long d = __hip_atomic_load(src + j, __ATOMIC_RELAXED,
                                                         __HIP_MEMORY_SCOPE_AGENT);
                int ko = j >> 4, b = (j >> 1) & 7, posq = (j & 1) << 2;
                *(unsigned long long*)&hA[(ko * 17 + b) * 8 + posq] = d;
            }
        }
        __syncthreads();

        // ---- h-part MFMA (K=1024), 2 accumulator chains ----
        f4v ah0 = {0.f, 0.f, 0.f, 0.f}, ah1 = {0.f, 0.f, 0.f, 0.f};
#pragma unroll
        for (int ks = 0; ks < 16; ++ks) {
            s8v a0 = *(const s8v*)&hA[((2 * ks) * 4 + q) * 17 * 8 + c * 8];
            s8v a1 = *(const s8v*)&hA[((2 * ks + 1) * 4 + q) * 17 * 8 + c * 8];
            ah0 = __builtin_amdgcn_mfma_f32_16x16x32_bf16(a0, Bh[2 * ks], ah0, 0, 0, 0);
            ah1 = __builtin_amdgcn_mfma_f32_16x16x32_bf16(a1, Bh[2 * ks + 1], ah1, 0, 0, 0);
        }

        // ---- dump gates ----
#pragma unroll
        for (int r = 0; r < 4; ++r)
            gbuf[(q * 4 + r) * 65 + v * 16 + c] = ae[r] + ah0[r] + ah1[r];
        __syncthreads();

        // ---- pointwise LSTM cell (64 threads x 2 cells) + publish ----
        if (tid < 64) {
            float h0, h1;
            {
                int pj = 2 * pj2, base = (pj >> 2) * 16, cb = pj & 3;
                float xi = gbuf[pb * 65 + base + cb]      + bi0;
                float xf = gbuf[pb * 65 + base + 4 + cb]  + bf0;
                float xg = gbuf[pb * 65 + base + 8 + cb]  + bg0;
                float xo = gbuf[pb * 65 + base + 12 + cb] + bo0;
                float ig = 1.f / (1.f + __expf(-xi));
                float fg = 1.f / (1.f + __expf(-xf));
                float gg = 1.f - 2.f / (1.f + __expf(2.f * xg));
                float og = 1.f / (1.f + __expf(-xo));
                cst0 = fg * cst0 + ig * gg;
                h0 = og * (1.f - 2.f / (1.f + __expf(2.f * cst0)));
            }
            {
                int pj = 2 * pj2 + 1, base = (pj >> 2) * 16, cb = pj & 3;
                float xi = gbuf[pb * 65 + base + cb]      + bi1;
                float xf = gbuf[pb * 65 + base + 4 + cb]  + bf1;
                float xg = gbuf[pb * 65 + base + 8 + cb]  + bg1;
                float xo = gbuf[pb * 65 + base + 12 + cb] + bo1;
                float ig = 1.f / (1.f + __expf(-xi));
                float fg = 1.f / (1.f + __expf(-xf));
                float gg = 1.f - 2.f / (1.f + __expf(2.f * xg));
                float og = 1.f / (1.f + __expf(-xo));
                cst1 = fg * cst1 + ig * gg;
                h1 = og * (1.f - 2.f / (1.f + __expf(2.f * cst1)));
            }
            unsigned int pack = (unsigned int)f2b(h0) | ((unsigned int)f2b(h1) << 16);
            __hip_atomic_store(&hb32[(rp ^ 1) * 4096 + dwidx], pack,
                               __ATOMIC_RELAXED, __HIP_MEMORY_SCOPE_AGENT);
            if (t == tvb)
                *(unsigned int*)&vrows[(b0 + pb) * 1024 + 16 * w + 2 * pj2] = pack;
        }
        __syncthreads();   // drains vmcnt(0): atomic stores are at LLC

        if (tid == 0)
            __hip_atomic_fetch_add(&mycnt[t], 1u, __ATOMIC_RELAXED,
                                   __HIP_MEMORY_SCOPE_AGENT);
        rp ^= 1;
    }

    // ---- tail: project h(510) (in hA), then fetch & project h(511) ----
    project_cols(hA, Wr0, Wr1, dout, b0, 510, w, tid);
    __syncthreads();   // hA reads done before overwrite
    while (__hip_atomic_load(&mycnt[511], __ATOMIC_RELAXED,
                             __HIP_MEMORY_SCOPE_AGENT) < 64u) {}
    {
        const unsigned long long* src = (const unsigned long long*)(hb + rp * 8192);
#pragma unroll
        for (int it = 0; it < 8; ++it) {
            int j = it * 256 + tid;
            unsigned long long d = __hip_atomic_load(src + j, __ATOMIC_RELAXED,
                                                     __HIP_MEMORY_SCOPE_AGENT);
            int ko = j >> 4, b = (j >> 1) & 7, posq = (j & 1) << 2;
            *(unsigned long long*)&hA[(ko * 17 + b) * 8 + posq] = d;
        }
    }
    __syncthreads();
    project_cols(hA, Wr0, Wr1, dout, b0, 511, w, tid);
}

// ---------------------------------------------------------------------------
// vlog[b][o] = vrows[b,:] . Wv[o,:] + b_lin[o]
// ---------------------------------------------------------------------------
__global__ void verb_kernel(const unsigned short* __restrict__ vrows,
                            const float* __restrict__ W_lin,
                            const float* __restrict__ b_lin,
                            float* __restrict__ vlog)
{
    __shared__ float vrow[1024];
    int b = blockIdx.x, tid = threadIdx.x;
    for (int i = tid; i < 1024; i += 256) vrow[i] = b2f(vrows[b * 1024 + i]);
    __syncthreads();
    if (tid < 128) {
        float acc = 0.f;
        const float* wr = W_lin + (size_t)tid * 2048;
        for (int h = 0; h < 1024; ++h) acc += vrow[h] * wr[h];
        vlog[b * 128 + tid] = acc + b_lin[tid];
    }
}

// ---------------------------------------------------------------------------
// In-place: dout[b,t,:] = log_softmax(dout[b,t,:] + vlog[b,:])
// ---------------------------------------------------------------------------
__global__ void softmax_kernel(float* __restrict__ dout,
                               const float* __restrict__ vlog)
{
    int tid = threadIdx.x;
    int grow = blockIdx.x * 32 + (tid >> 3);
    int part = tid & 7;
    int b = grow >> 9;
    float* pp = dout + (size_t)grow * 128 + part * 16;
    const float* vb = vlog + b * 128 + part * 16;
    float L[16];
#pragma unroll
    for (int i = 0; i < 16; ++i) L[i] = pp[i] + vb[i];
    float m = L[0];
#pragma unroll
    for (int i = 1; i < 16; ++i) m = fmaxf(m, L[i]);
    for (int off = 1; off < 8; off <<= 1) m = fmaxf(m, __shfl_xor(m, off));
    float s = 0.f;
#pragma unroll
    for (int i = 0; i < 16; ++i) s += expf(L[i] - m);
    for (int off = 1; off < 8; off <<= 1) s += __shfl_xor(s, off);
    float lz = m + logf(s);
#pragma unroll
    for (int i = 0; i < 16; ++i) pp[i] = L[i] - lz;
}

extern "C" void kernel_launch(void* const* d_in, const int* in_sizes, int n_in,
                              void* d_out, int out_size, void* d_ws, size_t ws_size,
                              hipStream_t stream) {
    const int*   tokens = (const int*)d_in[0];
    const int*   vidx   = (const int*)d_in[1];
    const float* emb    = (const float*)d_in[2];
    const float* W_ih   = (const float*)d_in[3];
    const float* W_hh   = (const float*)d_in[4];
    const float* b_ih   = (const float*)d_in[5];
    const float* b_hh   = (const float*)d_in[6];
    const float* W_lin  = (const float*)d_in[7];
    const float* b_lin  = (const float*)d_in[8];
    float* dout = (float*)d_out;

    char* ws = (char*)d_ws;
    unsigned short* hbuf  = (unsigned short*)ws;
    unsigned int*   cnt   = (unsigned int*)(ws + WS_CNT_OFF);
    unsigned short* vrows = (unsigned short*)(ws + WS_VROWS_OFF);
    float*          vlog  = (float*)(ws + WS_VLOG_OFF);

    init_kernel<<<136, 256, 0, stream>>>((unsigned int*)ws);
    scan_kernel<<<256, 256, 0, stream>>>(tokens, vidx, emb, W_ih, W_hh, b_ih, b_hh,
                                         W_lin, hbuf, cnt, vrows, dout);
    verb_kernel<<<32, 256, 0, stream>>>(vrows, W_lin, b_lin, vlog);
    softmax_kernel<<<512, 256, 0, stream>>>(dout, vlog);
}